// Round 9
// baseline (4608.139 us; speedup 1.0000x reference)
//
#include <hip/hip_runtime.h>
#include <math.h>

#define SS 2048
#define EE 1024
#define EPSD 1e-8
#define NTH 256          // 4 waves, 1 per SIMD
#define NW  4
#define NG  32           // cosine groups
#define GS  64           // group size

#define DPP_XOR1 0xB1    // quad_perm [1,0,3,2]
#define DPP_XOR2 0x4E    // quad_perm [2,3,0,1]
#define DPP_HMIR 0x141   // row_half_mirror
#define DPP_MIR  0x140   // row_mirror

template <typename T> struct VecT;
template <> struct VecT<double> { using t2 = double __attribute__((ext_vector_type(2))); };
template <> struct VecT<float>  { using t2 = float  __attribute__((ext_vector_type(2))); };

template <int CTRL>
__device__ __forceinline__ double mov_dpp_f64(double v) {
  union { double d; unsigned long long u; } a;
  a.d = v;
  const int lo = (int)(unsigned)(a.u & 0xFFFFFFFFull);
  const int hi = (int)(unsigned)(a.u >> 32);
  const int nlo = __builtin_amdgcn_mov_dpp(lo, CTRL, 0xF, 0xF, true);
  const int nhi = __builtin_amdgcn_mov_dpp(hi, CTRL, 0xF, 0xF, true);
  union { unsigned long long u; double d; } r;
  r.u = ((unsigned long long)(unsigned)nhi << 32) | (unsigned long long)(unsigned)nlo;
  return r.d;
}

template <int CTRL>
__device__ __forceinline__ double dpp_add(double v) { return v + mov_dpp_f64<CTRL>(v); }

template <int CTRL>
__device__ __forceinline__ void amax_dpp(double& v, int& ix) {
  const double ov = mov_dpp_f64<CTRL>(v);
  const int oi = __builtin_amdgcn_mov_dpp(ix, CTRL, 0xF, 0xF, true);
  if (ov > v || (ov == v && oi < ix)) { v = ov; ix = oi; }
}

__device__ __forceinline__ void amax_xor(double& v, int& ix, int m) {
  const double ov = __shfl_xor(v, m, 64);
  const int oi = __shfl_xor(ix, m, 64);
  if (ov > v || (ov == v && oi < ix)) { v = ov; ix = oi; }
}

__device__ __forceinline__ void foldmax(double& v, int& ix, double ov, int oi) {
  if (ov > v || (ov == v && oi < ix)) { v = ov; ix = oi; }
}

// 1/sqrt(x), ~1-2 ulp: v_rsq_f64 + 2 Newton iterations.
__device__ __forceinline__ double rsqrt2(double x) {
  double y = __builtin_amdgcn_rsq(x);
  const double h = 0.5 * x;
  y = y * fma(-h * y, y, 1.5);
  y = y * fma(-h * y, y, 1.5);
  return y;
}

// 1/x, ~1 ulp: v_rcp_f64 + 2 Newton iterations.
__device__ __forceinline__ double rcp2(double x) {
  double y = __builtin_amdgcn_rcp(x);
  y = y * fma(-x, y, 2.0);
  y = y * fma(-x, y, 2.0);
  return y;
}

__device__ __forceinline__ double wave_sum64(double v) {
#pragma unroll
  for (int off = 32; off > 0; off >>= 1) v += __shfl_down(v, off, 64);
  return v;
}

// ~1e-13-accurate branchless f64 tanh for |z| <~ 1.2.
__device__ __forceinline__ double tanh_fast(double z) {
  const double u = 0.5 * z;
  const double s = u * u;
  double p = -113927491862.0 / 2900518163668125.0;
  p = fma(p, s, 18888466084.0 / 194896477400625.0);
  p = fma(p, s, -443861162.0 / 1856156927625.0);
  p = fma(p, s, 6404582.0 / 10854718875.0);
  p = fma(p, s, -929569.0 / 638512875.0);
  p = fma(p, s, 21844.0 / 6081075.0);
  p = fma(p, s, -1382.0 / 155925.0);
  p = fma(p, s, 62.0 / 2835.0);
  p = fma(p, s, -17.0 / 315.0);
  p = fma(p, s, 2.0 / 15.0);
  p = fma(p, s, -1.0 / 3.0);
  const double t = fma(u * s, p, u);          // tanh(z/2)
  return (2.0 * t) * rcp2(fma(t, t, 1.0));
}

template <typename T>
__global__ void banyan_init(const int* __restrict__ seqs, const float* __restrict__ emb,
                            T* __restrict__ x, double* __restrict__ norms) {
  __shared__ double sh[4];
  const int s = blockIdx.x;
  const int row = seqs[s];
  double acc = 0.0;
  for (int e = threadIdx.x; e < EE; e += 256) {
    const float v = emb[(size_t)row * EE + e];
    x[(size_t)s * EE + e] = (T)v;
    acc += (double)v * (double)v;
  }
  acc = wave_sum64(acc);
  const int lane = threadIdx.x & 63;
  const int w = threadIdx.x >> 6;
  if (lane == 0) sh[w] = acc;
  __syncthreads();
  if (threadIdx.x == 0) norms[s] = sqrt(sh[0] + sh[1] + sh[2] + sh[3]);
}

template <typename T>
__global__ void banyan_dots(const T* __restrict__ x, double* __restrict__ num) {
  __shared__ double sh[4];
  const int s = blockIdx.x;
  double acc = 0.0;
  for (int e = threadIdx.x; e < EE; e += 256) {
    acc += (double)x[(size_t)s * EE + e] * (double)x[(size_t)(s + 1) * EE + e];
  }
  acc = wave_sum64(acc);
  const int lane = threadIdx.x & 63;
  const int w = threadIdx.x >> 6;
  if (lane == 0) sh[w] = acc;
  __syncthreads();
  if (threadIdx.x == 0) num[s] = sh[0] + sh[1] + sh[2] + sh[3];
}

// ONE barrier per merge step. Region k: fold(sums k-1) -> select quad k ->
// issue loads -> post writes(k-1) -> wave-split scans for k+1 -> tanh/reduce
// -> barrier. All reads that could alias in-flight writes are register-
// substituted; cross-region LDS handoffs (r3/r4/r5) double-buffered by parity.
template <typename T>
__global__ __launch_bounds__(NTH, 1) void banyan_main(
    T* __restrict__ x, const double* __restrict__ norms_in, const double* __restrict__ num_in,
    const float* __restrict__ Wl, const float* __restrict__ Wr, const float* __restrict__ Bb,
    float* __restrict__ out) {
  __shared__ double cosL[SS];
  __shared__ double rcpN[SS];      // 1 / max(norm, eps)
  __shared__ unsigned listL[SS];   // next lo16, prev hi16 (0xFFFF = -1)
  __shared__ int next2L[SS];       // next[next[s]] (-1 = none)
  __shared__ double gVal[NG];
  __shared__ int gIdx[NG];
  __shared__ double r3v[2][NW * 2 * 3];  // [parity][half-slot*3+c]
  __shared__ double r4v[2][3];           // stable-scan maxima (touched groups)
  __shared__ int r4i[2][3];
  __shared__ double r5v[2];              // S-scan result
  __shared__ int r5i[2][4];              // SiU, Snext, Sprev, next2S

  using T2 = typename VecT<T>::t2;
  const int t = threadIdx.x;
  const int lane = t & 63;
  const int w = t >> 6;
  const double NEGINF = -__builtin_inf();

  for (int s = t; s < SS; s += NTH) {
    rcpN[s] = 1.0 / fmax(norms_in[s], EPSD);
    const int nx = (s + 1 < SS) ? (s + 1) : -1;
    const int pv = s - 1;
    listL[s] = ((unsigned)nx & 0xFFFFu) | (((unsigned)pv & 0xFFFFu) << 16);
    next2L[s] = (s + 2 < SS) ? (s + 2) : -1;
  }
  __syncthreads();
  for (int s = t; s < SS; s += NTH) {
    cosL[s] = (s < SS - 1) ? (num_in[s] * rcpN[s]) * rcpN[s + 1] : NEGINF;
  }
  __syncthreads();
  for (int m = 0; m < NG / NW; ++m) {
    const int g = w * (NG / NW) + m;
    double v = cosL[g * GS + lane];
    int ix = g * GS + lane;
#pragma unroll
    for (int off = 32; off > 0; off >>= 1) {
      const double ov = __shfl_down(v, off, 64);
      const int oi = __shfl_down(ix, off, 64);
      if (ov > v || (ov == v && oi < ix)) { v = ov; ix = oi; }
    }
    if (lane == 0) { gVal[g] = v; gIdx[g] = ix; }
  }
  __syncthreads();

  // Thread t owns elements {2t, 2t+1, 512+2t, 512+2t+1}.
  const int e0 = 2 * t;
  const double wl0 = (double)Wl[e0],       wl1 = (double)Wl[e0 + 1];
  const double wl2 = (double)Wl[e0 + 512], wl3 = (double)Wl[e0 + 513];
  const double wr0 = (double)Wr[e0],       wr1 = (double)Wr[e0 + 1];
  const double wr2 = (double)Wr[e0 + 512], wr3 = (double)Wr[e0 + 513];
  const double bv0 = (double)Bb[e0],       bv1 = (double)Bb[e0 + 1];
  const double bv2 = (double)Bb[e0 + 512], bv3 = (double)Bb[e0 + 513];
  int head = 0;

  // ---- prologue: full argmax -> quad 0 -> issue loads ----
  int i, j, p, nj, p2, n2, j2;
  {
    double v = gVal[lane & 31];
    int ix = gIdx[lane & 31];
    amax_dpp<DPP_XOR1>(v, ix); amax_dpp<DPP_XOR2>(v, ix);
    amax_dpp<DPP_HMIR>(v, ix); amax_dpp<DPP_MIR>(v, ix);
    amax_xor(v, ix, 16);
    i = __builtin_amdgcn_readfirstlane(ix);
    const unsigned pki = listL[i];
    j = (int)(short)(pki & 0xFFFFu);
    p = (int)(short)(pki >> 16);
    nj = next2L[i];
    p2 = (p >= 0) ? p : i;
    n2 = (nj >= 0) ? nj : i;
    j2 = (j >= 0) ? j : i;
  }

  // merge-(k-1) substitution state (sentinels = no prev merge)
  int uLi = -1, uLp = -1, uLj = -1, uPP = -1, uN2P = -1;
  double uCosP = 0.0, uCosJ = 0.0, uInvnn = 0.0;
  unsigned uListJ = 0u, uListP = 0u;
  int ug0 = -1, ug1 = -1, ug2 = -1;
  double ugv0 = 0.0, ugv1 = 0.0, ugv2 = 0.0;
  int ugi0 = 0, ugi1 = 0, ugi2 = 0;
  // link data of the current quad (computed each region in [C])
  int ppPrev = -1, nj2JPrev = -1;
  unsigned listPPrev = 0u;
  double rcpPPrev = 0.0, rcpNNPrev = 0.0;

  T2 Lxi0, Lxi1, Lxj0, Lxj1, Lxp0, Lxp1, Lxn0, Lxn1;
#define ISSUE_LOADS(ia, ja, pa, na) do {                    \
    const int iM = (ia) & (SS - 1);                         \
    const int jM = (ja) & (SS - 1);                         \
    const int pM = (pa) & (SS - 1);                         \
    const int nM = (na) & (SS - 1);                         \
    Lxi0 = *(const T2*)&x[(size_t)iM * EE + e0];            \
    Lxi1 = *(const T2*)&x[(size_t)iM * EE + e0 + 512];      \
    Lxj0 = *(const T2*)&x[(size_t)jM * EE + e0];            \
    Lxj1 = *(const T2*)&x[(size_t)jM * EE + e0 + 512];      \
    Lxp0 = *(const T2*)&x[(size_t)pM * EE + e0];            \
    Lxp1 = *(const T2*)&x[(size_t)pM * EE + e0 + 512];      \
    Lxn0 = *(const T2*)&x[(size_t)nM * EE + e0];            \
    Lxn1 = *(const T2*)&x[(size_t)nM * EE + e0 + 512];      \
    __builtin_amdgcn_sched_barrier(0);                      \
  } while (0)
  ISSUE_LOADS(i, j2, p2, n2);

  for (int step = 0; step < SS - 1; ++step) {
    const int cur = step & 1;
    if (step) {
      // ---- [A] fold sums of merge step-1, select quad step ----
      const int prv = cur ^ 1;
      double t0 = 0.0, t1 = 0.0, t2 = 0.0;
#pragma unroll
      for (int m = 0; m < NW * 2; ++m) {
        t0 += r3v[prv][m * 3 + 0]; t1 += r3v[prv][m * 3 + 1]; t2 += r3v[prv][m * 3 + 2];
      }
      const double U0v = r4v[prv][0], U1v = r4v[prv][1], U2v = r4v[prv][2];
      const int U0i = r4i[prv][0], U1i = r4i[prv][1], U2i = r4i[prv][2];
      const double Sv = r5v[prv];
      const int SiU = r5i[prv][0], Snext = r5i[prv][1], Sprev = r5i[prv][2], next2S = r5i[prv][3];
      const double invnn = (t0 > EPSD * EPSD) ? rsqrt2(t0) : 1e8;
      const double cosP = (p >= 0) ? (t1 * rcpPPrev) * invnn : NEGINF;
      const double cosJ = (nj >= 0) ? (t2 * rcpNNPrev) * invnn : NEGINF;
      double bvv = Sv; int bii = SiU;
      foldmax(bvv, bii, U0v, U0i);
      foldmax(bvv, bii, U1v, U1i);
      foldmax(bvv, bii, U2v, U2i);
      foldmax(bvv, bii, cosP, p);
      foldmax(bvv, bii, cosJ, j);
      const int iN = __builtin_amdgcn_readfirstlane(bii);
      int jN, pN, njN;
      if (iN == p)        { jN = j;     pN = ppPrev; njN = nj;       }
      else if (iN == j)   { jN = nj;    pN = p;      njN = nj2JPrev; }
      else if (iN == SiU) { jN = Snext; pN = Sprev;  njN = next2S;   }
      else {
        const unsigned pk = listL[iN & (SS - 1)];
        jN = (int)(short)(pk & 0xFFFFu);
        pN = (int)(short)(pk >> 16);
        njN = next2L[iN & (SS - 1)];
      }
      if (iN != p && iN != j && iN == ppPrev) njN = j;  // next2 staleness fix
      const int j2N = (jN >= 0) ? jN : iN;
      const int p2N = (pN >= 0) ? pN : iN;
      const int n2N = (njN >= 0) ? njN : iN;
      // issue loads for quad step immediately (fly over writes+scans)
      ISSUE_LOADS(iN, j2N, p2N, n2N);

      // gVal folds for merge step-1 (all waves, uniform)
      const int g0 = i >> 6;
      const int g1 = (p >= 0) ? (p >> 6) : g0;
      const int g2 = j >> 6;
      double v0 = U0v; int x0 = U0i;
      if (p >= 0 && (p >> 6) == g0) foldmax(v0, x0, cosP, p);
      if ((j >> 6) == g0) foldmax(v0, x0, cosJ, j);
      double v1 = U1v; int x1 = U1i;
      if (p >= 0 && (p >> 6) == g1) foldmax(v1, x1, cosP, p);
      if ((j >> 6) == g1) foldmax(v1, x1, cosJ, j);
      double v2 = U2v; int x2 = U2i;
      if (p >= 0 && (p >> 6) == g2) foldmax(v2, x2, cosP, p);
      if ((j >> 6) == g2) foldmax(v2, x2, cosJ, j);

      // post writes for merge step-1
      const unsigned newListJ = ((unsigned)nj & 0xFFFFu) | (((unsigned)p & 0xFFFFu) << 16);
      const unsigned newListP = (listPPrev & 0xFFFF0000u) | ((unsigned)j & 0xFFFFu);
      if (w == 3) {
        if (lane == 0) {
          cosL[i] = NEGINF;
          cosL[j] = cosJ;
          rcpN[j] = invnn;
          listL[j] = newListJ;
          if (p >= 0) {
            cosL[p] = cosP;
            listL[p] = newListP;
            next2L[p] = nj;
            if (ppPrev >= 0) next2L[ppPrev] = j;
          }
        }
      } else if (lane == 0) {
        const int gw = (w == 0) ? g0 : (w == 1) ? g1 : g2;
        gVal[gw] = (w == 0) ? v0 : (w == 1) ? v1 : v2;
        gIdx[gw] = (w == 0) ? x0 : (w == 1) ? x1 : x2;
      }
      // substitution state = merge step-1's updates
      uLi = i; uLp = p; uLj = j; uPP = ppPrev; uN2P = nj;
      uCosP = cosP; uCosJ = cosJ; uInvnn = invnn;
      uListJ = newListJ; uListP = newListP;
      ug0 = g0; ug1 = g1; ug2 = g2;
      ugv0 = v0; ugv1 = v1; ugv2 = v2;
      ugi0 = x0; ugi1 = x1; ugi2 = x2;
      // commit quad step
      i = iN; j = jN; p = pN; nj = njN; j2 = j2N; p2 = p2N; n2 = n2N;
    }
    // ---- [B] head ----
    if (p < 0) head = j;
    const int gi_ = i >> 6;
    const int gp_ = (p >= 0) ? (p >> 6) : gi_;
    const int gj_ = j >> 6;

    // ---- [C] link pre-reads (subbed) + wave-split scans for step+1 ----
    {
      unsigned lp;
      if (p2 == uLj) lp = uListJ;
      else if (uLp >= 0 && p2 == uLp) lp = uListP;
      else lp = listL[p2];
      listPPrev = lp;
      ppPrev = (p >= 0) ? (int)(short)(lp >> 16) : -1;
      int n2j;
      if (uLp >= 0 && j2 == uLp) n2j = uN2P;
      else if (uPP >= 0 && j2 == uPP) n2j = uLj;
      else n2j = next2L[j2];
      nj2JPrev = n2j;
      rcpPPrev = (p2 == uLj) ? uInvnn : rcpN[p2];
      rcpNNPrev = (n2 == uLj) ? uInvnn : rcpN[n2];
    }
    if (w == 3) {  // S-scan over untouched groups
      const int g = lane & 31;
      double v = gVal[g];
      int ix = gIdx[g];
      if (uLi >= 0) {
        if (g == ug0) { v = ugv0; ix = ugi0; }
        if (g == ug1) { v = ugv1; ix = ugi1; }
        if (g == ug2) { v = ugv2; ix = ugi2; }
      }
      if (g == gi_ || g == gp_ || g == gj_) v = NEGINF;
      amax_dpp<DPP_XOR1>(v, ix); amax_dpp<DPP_XOR2>(v, ix);
      amax_dpp<DPP_HMIR>(v, ix); amax_dpp<DPP_MIR>(v, ix);
      amax_xor(v, ix, 16);
      const int SiU2 = __builtin_amdgcn_readfirstlane(ix);
      unsigned ls;
      if (SiU2 == uLj) ls = uListJ;
      else if (uLp >= 0 && SiU2 == uLp) ls = uListP;
      else ls = listL[SiU2];
      int n2s;
      if (uLp >= 0 && SiU2 == uLp) n2s = uN2P;
      else if (uPP >= 0 && SiU2 == uPP) n2s = uLj;
      else n2s = next2L[SiU2];
      if (lane == 0) {
        r5v[cur] = v;
        r5i[cur][0] = SiU2;
        r5i[cur][1] = (int)(short)(ls & 0xFFFFu);
        r5i[cur][2] = (int)(short)(ls >> 16);
        r5i[cur][3] = n2s;
      }
    } else {  // U-scans: stable slots of the 3 touched groups
      const int grp = (w == 0) ? gi_ : (w == 1) ? gp_ : gj_;
      const int pos = grp * GS + lane;
      double c = cosL[pos];
      if (uLi >= 0) {
        if (pos == uLi) c = NEGINF;
        if (uLp >= 0 && pos == uLp) c = uCosP;
        if (pos == uLj) c = uCosJ;
      }
      if (pos == i || pos == p || pos == j) c = NEGINF;
      int cx = pos;
      amax_dpp<DPP_XOR1>(c, cx); amax_dpp<DPP_XOR2>(c, cx);
      amax_dpp<DPP_HMIR>(c, cx); amax_dpp<DPP_MIR>(c, cx);
      amax_xor(c, cx, 16); amax_xor(c, cx, 32);
      if (lane == 0) { r4v[cur][w] = c; r4i[cur][w] = cx; }
    }

    // ---- [D] consume loads: tanh, store parent, fused 3-sum, reduce ----
    const double q0 = tanh_fast(fma((double)Lxi0.x, wl0, fma((double)Lxj0.x, wr0, bv0)));
    const double q1 = tanh_fast(fma((double)Lxi0.y, wl1, fma((double)Lxj0.y, wr1, bv1)));
    const double q2 = tanh_fast(fma((double)Lxi1.x, wl2, fma((double)Lxj1.x, wr2, bv2)));
    const double q3 = tanh_fast(fma((double)Lxi1.y, wl3, fma((double)Lxj1.y, wr3, bv3)));
    T2 st0; st0.x = (T)q0; st0.y = (T)q1;
    T2 st1; st1.x = (T)q2; st1.y = (T)q3;
    *(T2*)&x[(size_t)j * EE + e0] = st0;
    *(T2*)&x[(size_t)j * EE + e0 + 512] = st1;
    double s0 = fma(q0, q0, fma(q1, q1, fma(q2, q2, q3 * q3)));
    double s1 = fma((double)Lxp0.x, q0, fma((double)Lxp0.y, q1,
                fma((double)Lxp1.x, q2, (double)Lxp1.y * q3)));
    double s2 = fma(q0, (double)Lxn0.x, fma(q1, (double)Lxn0.y,
                fma(q2, (double)Lxn1.x, q3 * (double)Lxn1.y)));
    s1 = (p >= 0) ? s1 : 0.0;
    s2 = (nj >= 0) ? s2 : 0.0;
    s0 = dpp_add<DPP_XOR1>(s0); s1 = dpp_add<DPP_XOR1>(s1); s2 = dpp_add<DPP_XOR1>(s2);
    s0 = dpp_add<DPP_XOR2>(s0); s1 = dpp_add<DPP_XOR2>(s1); s2 = dpp_add<DPP_XOR2>(s2);
    s0 = dpp_add<DPP_HMIR>(s0); s1 = dpp_add<DPP_HMIR>(s1); s2 = dpp_add<DPP_HMIR>(s2);
    s0 = dpp_add<DPP_MIR>(s0);  s1 = dpp_add<DPP_MIR>(s1);  s2 = dpp_add<DPP_MIR>(s2);
    s0 += __shfl_xor(s0, 16, 64);
    s1 += __shfl_xor(s1, 16, 64);
    s2 += __shfl_xor(s2, 16, 64);
    if ((lane & 31) == 0) {
      const int slot = w * 2 + (lane >> 5);
      r3v[cur][slot * 3 + 0] = s0; r3v[cur][slot * 3 + 1] = s1; r3v[cur][slot * 3 + 2] = s2;
    }
    __syncthreads();  // the ONE barrier per step
  }
#undef ISSUE_LOADS

  {
    const T2 ha = *(const T2*)&x[(size_t)head * EE + e0];
    const T2 hb = *(const T2*)&x[(size_t)head * EE + e0 + 512];
    out[e0] = (float)ha.x;
    out[e0 + 1] = (float)ha.y;
    out[e0 + 512] = (float)hb.x;
    out[e0 + 513] = (float)hb.y;
  }
}

extern "C" void kernel_launch(void* const* d_in, const int* in_sizes, int n_in,
                              void* d_out, int out_size, void* d_ws, size_t ws_size,
                              hipStream_t stream) {
  const int* seqs = (const int*)d_in[0];
  const float* emb = (const float*)d_in[1];
  const float* Wl = (const float*)d_in[2];
  const float* Wr = (const float*)d_in[3];
  const float* Bb = (const float*)d_in[4];
  float* out = (float*)d_out;

  const size_t auxBytes = 2 * (size_t)SS * sizeof(double);
  const size_t xbytesD = (size_t)SS * EE * sizeof(double);

  if (ws_size >= xbytesD + auxBytes) {
    double* x = (double*)d_ws;
    double* norms = (double*)((char*)d_ws + xbytesD);
    double* num = norms + SS;
    hipLaunchKernelGGL((banyan_init<double>), dim3(SS), dim3(256), 0, stream, seqs, emb, x, norms);
    hipLaunchKernelGGL((banyan_dots<double>), dim3(SS - 1), dim3(256), 0, stream, x, num);
    hipLaunchKernelGGL((banyan_main<double>), dim3(1), dim3(NTH), 0, stream,
                       x, norms, num, Wl, Wr, Bb, out);
  } else {
    const size_t xbytesF = (size_t)SS * EE * sizeof(float);
    float* x = (float*)d_ws;
    double* norms = (double*)((char*)d_ws + xbytesF);
    double* num = norms + SS;
    hipLaunchKernelGGL((banyan_init<float>), dim3(SS), dim3(256), 0, stream, seqs, emb, x, norms);
    hipLaunchKernelGGL((banyan_dots<float>), dim3(SS - 1), dim3(256), 0, stream, x, num);
    hipLaunchKernelGGL((banyan_main<float>), dim3(1), dim3(NTH), 0, stream,
                       x, norms, num, Wl, Wr, Bb, out);
  }
}

// Round 11
// 3545.972 us; speedup vs baseline: 1.2995x; 1.2995x over previous
//
#include <hip/hip_runtime.h>
#include <math.h>

#define SS 2048
#define EE 1024
#define EPSD 1e-8
#define NTH 256          // 4 waves, 1 per SIMD
#define NW  4
#define NG  32           // cosine groups
#define GS  64           // group size

#define DPP_XOR1 0xB1    // quad_perm [1,0,3,2]
#define DPP_XOR2 0x4E    // quad_perm [2,3,0,1]
#define DPP_HMIR 0x141   // row_half_mirror
#define DPP_MIR  0x140   // row_mirror

template <typename T> struct VecT;
template <> struct VecT<double> { using t2 = double __attribute__((ext_vector_type(2))); };
template <> struct VecT<float>  { using t2 = float  __attribute__((ext_vector_type(2))); };

template <int CTRL>
__device__ __forceinline__ double mov_dpp_f64(double v) {
  union { double d; unsigned long long u; } a;
  a.d = v;
  const int lo = (int)(unsigned)(a.u & 0xFFFFFFFFull);
  const int hi = (int)(unsigned)(a.u >> 32);
  const int nlo = __builtin_amdgcn_mov_dpp(lo, CTRL, 0xF, 0xF, true);
  const int nhi = __builtin_amdgcn_mov_dpp(hi, CTRL, 0xF, 0xF, true);
  union { unsigned long long u; double d; } r;
  r.u = ((unsigned long long)(unsigned)nhi << 32) | (unsigned long long)(unsigned)nlo;
  return r.d;
}

template <int CTRL>
__device__ __forceinline__ double dpp_add(double v) { return v + mov_dpp_f64<CTRL>(v); }

template <int CTRL>
__device__ __forceinline__ void amax_dpp(double& v, int& ix) {
  const double ov = mov_dpp_f64<CTRL>(v);
  const int oi = __builtin_amdgcn_mov_dpp(ix, CTRL, 0xF, 0xF, true);
  if (ov > v || (ov == v && oi < ix)) { v = ov; ix = oi; }
}

__device__ __forceinline__ void foldmax(double& v, int& ix, double ov, int oi) {
  if (ov > v || (ov == v && oi < ix)) { v = ov; ix = oi; }
}

// 1/sqrt(x), ~1-2 ulp: v_rsq_f64 + 2 Newton iterations. (decision-safe: R6-R9)
__device__ __forceinline__ double rsqrt2(double x) {
  double y = __builtin_amdgcn_rsq(x);
  const double h = 0.5 * x;
  y = y * fma(-h * y, y, 1.5);
  y = y * fma(-h * y, y, 1.5);
  return y;
}

// 1/x, ~1 ulp: v_rcp_f64 + 2 Newton iterations. (decision-safe: R8-R9)
__device__ __forceinline__ double rcp2(double x) {
  double y = __builtin_amdgcn_rcp(x);
  y = y * fma(-x, y, 2.0);
  y = y * fma(-x, y, 2.0);
  return y;
}

__device__ __forceinline__ double wave_sum64(double v) {
#pragma unroll
  for (int off = 32; off > 0; off >>= 1) v += __shfl_down(v, off, 64);
  return v;
}

// ~1e-13-accurate branchless f64 tanh for |z| <~ 1.2.
__device__ __forceinline__ double tanh_fast(double z) {
  const double u = 0.5 * z;
  const double s = u * u;
  double p = -113927491862.0 / 2900518163668125.0;
  p = fma(p, s, 18888466084.0 / 194896477400625.0);
  p = fma(p, s, -443861162.0 / 1856156927625.0);
  p = fma(p, s, 6404582.0 / 10854718875.0);
  p = fma(p, s, -929569.0 / 638512875.0);
  p = fma(p, s, 21844.0 / 6081075.0);
  p = fma(p, s, -1382.0 / 155925.0);
  p = fma(p, s, 62.0 / 2835.0);
  p = fma(p, s, -17.0 / 315.0);
  p = fma(p, s, 2.0 / 15.0);
  p = fma(p, s, -1.0 / 3.0);
  const double t = fma(u * s, p, u);          // tanh(z/2)
  return (2.0 * t) * rcp2(fma(t, t, 1.0));
}

template <typename T>
__global__ void banyan_init(const int* __restrict__ seqs, const float* __restrict__ emb,
                            T* __restrict__ x, double* __restrict__ norms) {
  __shared__ double sh[4];
  const int s = blockIdx.x;
  const int row = seqs[s];
  double acc = 0.0;
  for (int e = threadIdx.x; e < EE; e += 256) {
    const float v = emb[(size_t)row * EE + e];
    x[(size_t)s * EE + e] = (T)v;
    acc += (double)v * (double)v;
  }
  acc = wave_sum64(acc);
  const int lane = threadIdx.x & 63;
  const int w = threadIdx.x >> 6;
  if (lane == 0) sh[w] = acc;
  __syncthreads();
  if (threadIdx.x == 0) norms[s] = sqrt(sh[0] + sh[1] + sh[2] + sh[3]);
}

template <typename T>
__global__ void banyan_dots(const T* __restrict__ x, double* __restrict__ num) {
  __shared__ double sh[4];
  const int s = blockIdx.x;
  double acc = 0.0;
  for (int e = threadIdx.x; e < EE; e += 256) {
    acc += (double)x[(size_t)s * EE + e] * (double)x[(size_t)(s + 1) * EE + e];
  }
  acc = wave_sum64(acc);
  const int lane = threadIdx.x & 63;
  const int w = threadIdx.x >> 6;
  if (lane == 0) sh[w] = acc;
  __syncthreads();
  if (threadIdx.x == 0) num[s] = sh[0] + sh[1] + sh[2] + sh[3];
}

// R4 (best) structure, crossing-free: every cross-lane reduction is
// multi-slot-LDS-load + in-register fold + 4-stage DPP row-reduce.
// No ds_bpermute / shfl / permlane in the steady-state loop. 2 barriers/step.
template <typename T>
__global__ __launch_bounds__(NTH, 1) void banyan_main(
    T* __restrict__ x, const double* __restrict__ norms_in, const double* __restrict__ num_in,
    const float* __restrict__ Wl, const float* __restrict__ Wr, const float* __restrict__ Bb,
    float* __restrict__ out) {
  __shared__ double cosL[SS];
  __shared__ double rcpN[SS];      // 1 / max(norm, eps)
  __shared__ unsigned listL[SS];   // next lo16, prev hi16 (0xFFFF = -1)
  __shared__ int next2L[SS];       // next[next[s]] (-1 = none)
  __shared__ double gVal[NG];
  __shared__ int gIdx[NG];
  __shared__ double r3v[3][16];    // [sum][row-slot: w*4 + row]

  using T2 = typename VecT<T>::t2;
  const int t = threadIdx.x;
  const int lane = t & 63;
  const int w = t >> 6;
  const int m16 = lane & 15;
  const double NEGINF = -__builtin_inf();

  for (int s = t; s < SS; s += NTH) {
    rcpN[s] = 1.0 / fmax(norms_in[s], EPSD);
    const int nx = (s + 1 < SS) ? (s + 1) : -1;
    const int pv = s - 1;
    listL[s] = ((unsigned)nx & 0xFFFFu) | (((unsigned)pv & 0xFFFFu) << 16);
    next2L[s] = (s + 2 < SS) ? (s + 2) : -1;
  }
  __syncthreads();
  for (int s = t; s < SS; s += NTH) {
    cosL[s] = (s < SS - 1) ? (num_in[s] * rcpN[s]) * rcpN[s + 1] : NEGINF;
  }
  __syncthreads();
  for (int m = 0; m < NG / NW; ++m) {
    const int g = w * (NG / NW) + m;
    double v = cosL[g * GS + lane];
    int ix = g * GS + lane;
#pragma unroll
    for (int off = 32; off > 0; off >>= 1) {
      const double ov = __shfl_down(v, off, 64);
      const int oi = __shfl_down(ix, off, 64);
      if (ov > v || (ov == v && oi < ix)) { v = ov; ix = oi; }
    }
    if (lane == 0) { gVal[g] = v; gIdx[g] = ix; }
  }
  __syncthreads();

  // Thread t owns elements {2t, 2t+1, 512+2t, 512+2t+1}.
  const int e0 = 2 * t;
  const double wl0 = (double)Wl[e0],       wl1 = (double)Wl[e0 + 1];
  const double wl2 = (double)Wl[e0 + 512], wl3 = (double)Wl[e0 + 513];
  const double wr0 = (double)Wr[e0],       wr1 = (double)Wr[e0 + 1];
  const double wr2 = (double)Wr[e0 + 512], wr3 = (double)Wr[e0 + 513];
  const double bv0 = (double)Bb[e0],       bv1 = (double)Bb[e0 + 1];
  const double bv2 = (double)Bb[e0 + 512], bv3 = (double)Bb[e0 + 513];
  int head = 0;

  for (int step = 0; step < SS - 1; ++step) {
    // ---- phase 1: argmax over 32 group maxima, crossing-free ----
    // Each lane folds groups m16 and m16+16, then 4-stage DPP row-reduce.
    double v = gVal[m16];
    int ix = gIdx[m16];
    {
      const double vB = gVal[m16 + 16];
      const int iB = gIdx[m16 + 16];
      foldmax(v, ix, vB, iB);
    }
    amax_dpp<DPP_XOR1>(v, ix);
    amax_dpp<DPP_XOR2>(v, ix);
    amax_dpp<DPP_HMIR>(v, ix);
    amax_dpp<DPP_MIR>(v, ix);
    const int i = __builtin_amdgcn_readfirstlane(ix);
    // issue i-row loads immediately (don't wait for the list round-trip)
    const T2 xiA = *(const T2*)&x[(size_t)i * EE + e0];
    const T2 xiB = *(const T2*)&x[(size_t)i * EE + e0 + 512];
    const unsigned pki = listL[i];   // broadcast LDS reads
    const int nj_raw = next2L[i];
    const int j = __builtin_amdgcn_readfirstlane((int)(short)(pki & 0xFFFFu));
    const int p = __builtin_amdgcn_readfirstlane((int)(short)(pki >> 16));
    const int nj = __builtin_amdgcn_readfirstlane(nj_raw);
    if (p < 0) head = j;
    const int p2 = (p >= 0) ? p : i;
    const int n2 = (nj >= 0) ? nj : i;

    // ---- phase 2: remaining loads in one window, tanh, row-partial sums ----
    const T2 xjA = *(const T2*)&x[(size_t)j * EE + e0];
    const T2 xjB = *(const T2*)&x[(size_t)j * EE + e0 + 512];
    const T2 xpA = *(const T2*)&x[(size_t)p2 * EE + e0];
    const T2 xpB = *(const T2*)&x[(size_t)p2 * EE + e0 + 512];
    const T2 xnA = *(const T2*)&x[(size_t)n2 * EE + e0];
    const T2 xnB = *(const T2*)&x[(size_t)n2 * EE + e0 + 512];
    const double rcpP = rcpN[p2];
    const double rcpNN = rcpN[n2];
    const int gi_ = i >> 6;
    const int gp_ = (p >= 0) ? (p >> 6) : gi_;
    const int gj_ = j >> 6;
    const int grp = (w == 0) ? gi_ : (w == 1) ? gp_ : gj_;
    const int base = grp * GS + m16;
    // repair-group preloads: 4 slots/lane (same-address 4-way broadcast, free)
    const double c0 = cosL[base];
    const double c1 = cosL[base + 16];
    const double c2 = cosL[base + 32];
    const double c3 = cosL[base + 48];

    const double q0 = tanh_fast(fma((double)xiA.x, wl0, fma((double)xjA.x, wr0, bv0)));
    const double q1 = tanh_fast(fma((double)xiA.y, wl1, fma((double)xjA.y, wr1, bv1)));
    const double q2 = tanh_fast(fma((double)xiB.x, wl2, fma((double)xjB.x, wr2, bv2)));
    const double q3 = tanh_fast(fma((double)xiB.y, wl3, fma((double)xjB.y, wr3, bv3)));
    T2 st0; st0.x = (T)q0; st0.y = (T)q1;
    T2 st1; st1.x = (T)q2; st1.y = (T)q3;
    *(T2*)&x[(size_t)j * EE + e0] = st0;
    *(T2*)&x[(size_t)j * EE + e0 + 512] = st1;

    double s0 = fma(q0, q0, fma(q1, q1, fma(q2, q2, q3 * q3)));
    double s1 = fma((double)xpA.x, q0, fma((double)xpA.y, q1,
                fma((double)xpB.x, q2, (double)xpB.y * q3)));
    double s2 = fma(q0, (double)xnA.x, fma(q1, (double)xnA.y,
                fma(q2, (double)xnB.x, q3 * (double)xnB.y)));
    s1 = (p >= 0) ? s1 : 0.0;
    s2 = (nj >= 0) ? s2 : 0.0;
    // DPP-only row reduce (16-lane rows); write 16 row partials
    s0 = dpp_add<DPP_XOR1>(s0); s1 = dpp_add<DPP_XOR1>(s1); s2 = dpp_add<DPP_XOR1>(s2);
    s0 = dpp_add<DPP_XOR2>(s0); s1 = dpp_add<DPP_XOR2>(s1); s2 = dpp_add<DPP_XOR2>(s2);
    s0 = dpp_add<DPP_HMIR>(s0); s1 = dpp_add<DPP_HMIR>(s1); s2 = dpp_add<DPP_HMIR>(s2);
    s0 = dpp_add<DPP_MIR>(s0);  s1 = dpp_add<DPP_MIR>(s1);  s2 = dpp_add<DPP_MIR>(s2);
    if (m16 == 0) {                  // lanes 0,16,32,48: row partials
      const int slot = w * 4 + (lane >> 4);
      r3v[0][slot] = s0; r3v[1][slot] = s1; r3v[2][slot] = s2;
    }
    __syncthreads();  // B

    // ---- phase 3: DPP fold of 16 partials + cosines + crossing-free repair ----
    double t0 = r3v[0][m16];
    double t1 = r3v[1][m16];
    double t2 = r3v[2][m16];
    t0 = dpp_add<DPP_XOR1>(t0); t1 = dpp_add<DPP_XOR1>(t1); t2 = dpp_add<DPP_XOR1>(t2);
    t0 = dpp_add<DPP_XOR2>(t0); t1 = dpp_add<DPP_XOR2>(t1); t2 = dpp_add<DPP_XOR2>(t2);
    t0 = dpp_add<DPP_HMIR>(t0); t1 = dpp_add<DPP_HMIR>(t1); t2 = dpp_add<DPP_HMIR>(t2);
    t0 = dpp_add<DPP_MIR>(t0);  t1 = dpp_add<DPP_MIR>(t1);  t2 = dpp_add<DPP_MIR>(t2);
    const double invnn = (t0 > EPSD * EPSD) ? rsqrt2(t0) : 1e8;
    const double cosP = (p >= 0) ? (t1 * rcpP) * invnn : NEGINF;
    const double cosJnew = (nj >= 0) ? (t2 * rcpNN) * invnn : NEGINF;
    if (w < 3) {
      // substitute the 3 changed slots, fold 4-in-register, DPP row-reduce
      double cc0 = c0, cc1 = c1, cc2 = c2, cc3 = c3;
      const int pos0 = base, pos1 = base + 16, pos2 = base + 32, pos3 = base + 48;
      if (pos0 == i) cc0 = NEGINF;
      if (p >= 0 && pos0 == p) cc0 = cosP;
      if (pos0 == j) cc0 = cosJnew;
      if (pos1 == i) cc1 = NEGINF;
      if (p >= 0 && pos1 == p) cc1 = cosP;
      if (pos1 == j) cc1 = cosJnew;
      if (pos2 == i) cc2 = NEGINF;
      if (p >= 0 && pos2 == p) cc2 = cosP;
      if (pos2 == j) cc2 = cosJnew;
      if (pos3 == i) cc3 = NEGINF;
      if (p >= 0 && pos3 == p) cc3 = cosP;
      if (pos3 == j) cc3 = cosJnew;
      double cv = cc0; int gx = pos0;
      foldmax(cv, gx, cc1, pos1);
      foldmax(cv, gx, cc2, pos2);
      foldmax(cv, gx, cc3, pos3);
      amax_dpp<DPP_XOR1>(cv, gx);
      amax_dpp<DPP_XOR2>(cv, gx);
      amax_dpp<DPP_HMIR>(cv, gx);
      amax_dpp<DPP_MIR>(cv, gx);
      if (lane == 0) { gVal[grp] = cv; gIdx[grp] = gx; }  // dup groups: same value
    } else if (lane == 0) {  // wave 3: scalar LDS state updates
      cosL[i] = NEGINF;
      cosL[j] = cosJnew;
      rcpN[j] = invnn;
      listL[j] = ((unsigned)nj & 0xFFFFu) | (((unsigned)p & 0xFFFFu) << 16);
      if (p >= 0) {
        cosL[p] = cosP;
        const unsigned lp = listL[p];
        listL[p] = (lp & 0xFFFF0000u) | ((unsigned)j & 0xFFFFu);
        next2L[p] = nj;
        const int pp = (int)(short)(lp >> 16);
        if (pp >= 0) next2L[pp] = j;
      }
    }
    __syncthreads();  // C
  }

  {
    const T2 ha = *(const T2*)&x[(size_t)head * EE + e0];
    const T2 hb = *(const T2*)&x[(size_t)head * EE + e0 + 512];
    out[e0] = (float)ha.x;
    out[e0 + 1] = (float)ha.y;
    out[e0 + 512] = (float)hb.x;
    out[e0 + 513] = (float)hb.y;
  }
}

extern "C" void kernel_launch(void* const* d_in, const int* in_sizes, int n_in,
                              void* d_out, int out_size, void* d_ws, size_t ws_size,
                              hipStream_t stream) {
  const int* seqs = (const int*)d_in[0];
  const float* emb = (const float*)d_in[1];
  const float* Wl = (const float*)d_in[2];
  const float* Wr = (const float*)d_in[3];
  const float* Bb = (const float*)d_in[4];
  float* out = (float*)d_out;

  const size_t auxBytes = 2 * (size_t)SS * sizeof(double);
  const size_t xbytesD = (size_t)SS * EE * sizeof(double);

  if (ws_size >= xbytesD + auxBytes) {
    double* x = (double*)d_ws;
    double* norms = (double*)((char*)d_ws + xbytesD);
    double* num = norms + SS;
    hipLaunchKernelGGL((banyan_init<double>), dim3(SS), dim3(256), 0, stream, seqs, emb, x, norms);
    hipLaunchKernelGGL((banyan_dots<double>), dim3(SS - 1), dim3(256), 0, stream, x, num);
    hipLaunchKernelGGL((banyan_main<double>), dim3(1), dim3(NTH), 0, stream,
                       x, norms, num, Wl, Wr, Bb, out);
  } else {
    const size_t xbytesF = (size_t)SS * EE * sizeof(float);
    float* x = (float*)d_ws;
    double* norms = (double*)((char*)d_ws + xbytesF);
    double* num = norms + SS;
    hipLaunchKernelGGL((banyan_init<float>), dim3(SS), dim3(256), 0, stream, seqs, emb, x, norms);
    hipLaunchKernelGGL((banyan_dots<float>), dim3(SS - 1), dim3(256), 0, stream, x, num);
    hipLaunchKernelGGL((banyan_main<float>), dim3(1), dim3(NTH), 0, stream,
                       x, norms, num, Wl, Wr, Bb, out);
  }
}